// Round 2
// baseline (3693.368 us; speedup 1.0000x reference)
//
#include <hip/hip_runtime.h>

// MonarchAttentionPerformer on MI355X — round 2: dtype-agnostic correctness.
// Round-1 NaN diagnosis: inputs are most likely fp32 (reference dtype), and
// reading fp32 as bf16 pairs yields NaN patterns (~1/256 of low halves).
// This version detects the on-device dtype at runtime (uniform branch) and
// works for either fp32 or bf16 storage, including the output store.
//
// Pipeline (N=32768 tokens, D=768, M=384, batches B=8 x T=4096):
//   cvt: x -> x32 (fp32), biases -> fp32
//   G1: KQV = X @ Wkqv + b         (K,Q -> fp32 KQ; V -> bf16)
//   xd[part][t] = 0.5*||row||^2
//   G2: kp = exp(K @ wT - xd_k)/sqrt(M), qp likewise  (bf16)
//   ksum[b][m] = sum_t kp
//   G3: kptvT[b][m][n] = sum_t kp[t][m] * V[t][n]     (fp32)
//   D[t] = qp[t] . ksum[b]
//   G4: Y = (qp @ kptvT) / (D + 1e-8)                 (bf16)
//   G5: OUT = Y @ Wproj + bp                          (flag: bf16 or fp32)

#define NTOK   32768
#define RSQRTM 0.05103103630798288f   // 1/sqrt(384)

__device__ __forceinline__ float b2f(unsigned short u){
  union{unsigned int i; float f;} v; v.i = ((unsigned int)u)<<16; return v.f;
}
__device__ __forceinline__ unsigned short f2b(float f){
  union{float f; unsigned int i;} v; v.f = f;
  unsigned int x = v.i;
  x += 0x7fffu + ((x>>16)&1u);      // round-to-nearest-even
  return (unsigned short)(x>>16);
}
__device__ __forceinline__ void ld4(const float* p, float o[4]){
  const float4 v = *reinterpret_cast<const float4*>(p);
  o[0]=v.x; o[1]=v.y; o[2]=v.z; o[3]=v.w;
}
__device__ __forceinline__ void ld4(const unsigned short* p, float o[4]){
  const ushort4 v = *reinterpret_cast<const ushort4*>(p);
  o[0]=b2f(v.x); o[1]=b2f(v.y); o[2]=b2f(v.z); o[3]=b2f(v.w);
}
// flag-aware scalar load of input tensors (flag: 1 = fp32 storage, 0 = bf16)
__device__ __forceinline__ float gf(const void* p, int i, int f){
  return f ? ((const float*)p)[i] : b2f(((const unsigned short*)p)[i]);
}

// ---------------- dtype detection ----------------
// fp32 N(0,1) data: exponent field of raw words lies in [0x60,0x9F].
// bf16-packed pairs: composed exponent field = (bf16 exp low bits | mant bit),
// which lands near 0x00-0x03 or 0xF0-0xFF for unit-scale data — out of band.
__global__ void detect_dtype(const unsigned int* __restrict__ x, int* __restrict__ flag){
  __shared__ int cnt;
  if (threadIdx.x == 0) cnt = 0;
  __syncthreads();
  const unsigned int v = x[threadIdx.x];
  const int e = (v >> 23) & 0xFF;
  if (e >= 0x60 && e <= 0x9F) atomicAdd(&cnt, 1);
  __syncthreads();
  if (threadIdx.x == 0) flag[0] = (cnt >= 128) ? 1 : 0;
}

__global__ void cvt_kernel(const void* __restrict__ src, float* __restrict__ dst,
                           int n, const int* __restrict__ flagp){
  const int i = blockIdx.x*256 + threadIdx.x;
  if (i >= n) return;
  dst[i] = gf(src, i, *flagp);
}

// ---------------- dense-W builders ----------------
// Wdense[k*192+p][s*4+l] = sum_u w1[k][l*48+u][p] * w2[l][s][4u+k]
__global__ void build_wkqv(const void* __restrict__ w1, const void* __restrict__ w2,
                           float* __restrict__ W, const int* __restrict__ flagp){
  const int f = *flagp;
  const int idx = blockIdx.x*256 + threadIdx.x;       // 768*2304
  const int i = idx / 2304, j = idx % 2304;
  const int k = i / 192,  p = i % 192;
  const int s = j >> 2,   l = j & 3;
  float acc = 0.f;
  #pragma unroll 4
  for(int u=0; u<48; ++u)
    acc += gf(w1, (k*192 + l*48+u)*192 + p, f) * gf(w2, (l*576+s)*192 + 4*u+k, f);
  W[idx] = acc;
}
__global__ void build_wproj(const void* __restrict__ w1, const void* __restrict__ w2,
                            float* __restrict__ W, const int* __restrict__ flagp){
  const int f = *flagp;
  const int idx = blockIdx.x*256 + threadIdx.x;       // 768*768
  const int i = idx / 768, j = idx % 768;
  const int k = i / 192,  p = i % 192;
  const int s = j >> 2,   l = j & 3;
  float acc = 0.f;
  #pragma unroll 4
  for(int u=0; u<48; ++u)
    acc += gf(w1, (k*192 + l*48+u)*192 + p, f) * gf(w2, (l*192+s)*192 + 4*u+k, f);
  W[idx] = acc;
}
__global__ void transpose_w(const void* __restrict__ w, float* __restrict__ wT,
                            const int* __restrict__ flagp){
  const int f = *flagp;
  const int o = blockIdx.x*256 + threadIdx.x;         // 768*384
  const int i = o / 384, m = o % 384;
  wT[o] = gf(w, m*768 + i, f);
}

// ---------------- generic tiled GEMM ----------------
// C[m][n] = sum_k A(m,k) * B[k][n]; A(m,k) = A[m*lda+k] (!TRA) or A[k*lda+m] (TRA).
// 256 threads; (BM/TM)*(BN/TN) must be 256. BK=16.
// EPI: 0 = +bias(fp32), split KQ(fp32,ld 1536)/V(bf16,ld 768)
//      1 = exp(acc - xd[row])*RSQRTM -> bf16
//      2 = fp32 store
//      3 = acc / (D[row]+1e-8) -> bf16
//      4 = +bias(fp32) -> bf16 or fp32 per *flagp
template<int BM,int BN,int TM,int TN, typename TAt, typename TBt, bool TRA, int EPI>
__global__ __launch_bounds__(256)
void gemm_k(const TAt* __restrict__ A, int lda, long aBatch,
            const TBt* __restrict__ B, int ldb, long bBatch,
            int K, int ldo, long outBatch,
            void* __restrict__ out, void* __restrict__ out2,
            const void* __restrict__ aux, long auxBatch,
            const int* __restrict__ flagp){
  constexpr int BK    = 16;
  constexpr int LDA_S = BM + 4;
  constexpr int LDB_S = BN + 4;
  __shared__ float As[BK*LDA_S];
  __shared__ float Bs[BK*LDB_S];

  const int tid = threadIdx.x;
  const int bz  = blockIdx.z;
  const TAt* Ab = A + (long)bz*aBatch;
  const TBt* Bb = B + (long)bz*bBatch;
  const int m0 = blockIdx.y*BM, n0 = blockIdx.x*BN;
  const int tr = tid >> 4, tc = tid & 15;

  float acc[TM][TN];
  #pragma unroll
  for(int i=0;i<TM;i++)
    #pragma unroll
    for(int j=0;j<TN;j++) acc[i][j]=0.f;

  for(int k0=0; k0<K; k0+=BK){
    // stage A
    if constexpr(!TRA){
      constexpr int NVA = (BM*BK/4)/256;
      #pragma unroll
      for(int i=0;i<NVA;i++){
        const int e  = tid + 256*i;
        const int k4 = (e & 3) * 4;
        const int m  = e >> 2;
        float t4[4]; ld4(Ab + (long)(m0+m)*lda + k0 + k4, t4);
        #pragma unroll
        for(int j=0;j<4;j++) As[(k4+j)*LDA_S + m] = t4[j];
      }
    } else {
      constexpr int NVA = (BK*(BM/4))/256;
      #pragma unroll
      for(int i=0;i<NVA;i++){
        const int e  = tid + 256*i;
        const int m4 = (e % (BM/4)) * 4;
        const int k  = e / (BM/4);
        float t4[4]; ld4(Ab + (long)(k0+k)*lda + m0 + m4, t4);
        float4 s; s.x=t4[0]; s.y=t4[1]; s.z=t4[2]; s.w=t4[3];
        *reinterpret_cast<float4*>(&As[k*LDA_S + m4]) = s;
      }
    }
    // stage B (row-major K x N)
    {
      constexpr int NVB = (BK*(BN/4))/256;
      #pragma unroll
      for(int i=0;i<NVB;i++){
        const int e  = tid + 256*i;
        const int n4 = (e % (BN/4)) * 4;
        const int k  = e / (BN/4);
        float t4[4]; ld4(Bb + (long)(k0+k)*ldb + n0 + n4, t4);
        float4 s; s.x=t4[0]; s.y=t4[1]; s.z=t4[2]; s.w=t4[3];
        *reinterpret_cast<float4*>(&Bs[k*LDB_S + n4]) = s;
      }
    }
    __syncthreads();
    #pragma unroll
    for(int kk=0;kk<BK;kk++){
      float a[TM], b[TN];
      #pragma unroll
      for(int t=0;t<TM/4;t++){
        const float4 v = *reinterpret_cast<const float4*>(&As[kk*LDA_S + tr*TM + 4*t]);
        a[4*t]=v.x; a[4*t+1]=v.y; a[4*t+2]=v.z; a[4*t+3]=v.w;
      }
      #pragma unroll
      for(int t=0;t<TN/4;t++){
        const float4 v = *reinterpret_cast<const float4*>(&Bs[kk*LDB_S + tc*TN + 4*t]);
        b[4*t]=v.x; b[4*t+1]=v.y; b[4*t+2]=v.z; b[4*t+3]=v.w;
      }
      #pragma unroll
      for(int i=0;i<TM;i++)
        #pragma unroll
        for(int j=0;j<TN;j++) acc[i][j] = fmaf(a[i], b[j], acc[i][j]);
    }
    __syncthreads();
  }

  const long rbase = (long)blockIdx.y*BM + tr*TM;
  const int  cbase = n0 + tc*TN;

  if constexpr(EPI==0){
    const float* bias = (const float*)aux;
    float* KQ = (float*)out; unsigned short* V = (unsigned short*)out2;
    #pragma unroll
    for(int i=0;i<TM;i++){ const long r = rbase+i;
      #pragma unroll
      for(int j=0;j<TN;j++){ const int c = cbase+j;
        const float v = acc[i][j] + bias[c];
        if (c < 1536) KQ[r*1536 + c] = v;
        else          V[r*768 + (c-1536)] = f2b(v);
      }
    }
  } else if constexpr(EPI==1){
    const float* xd = (const float*)aux;
    unsigned short* o = (unsigned short*)out;
    #pragma unroll
    for(int i=0;i<TM;i++){ const long r = rbase+i; const float xv = xd[r];
      #pragma unroll
      for(int j=0;j<TN;j++)
        o[r*ldo + cbase+j] = f2b(__expf(acc[i][j]-xv)*RSQRTM);
    }
  } else if constexpr(EPI==2){
    float* o = (float*)out + (long)bz*outBatch;
    #pragma unroll
    for(int i=0;i<TM;i++)
      #pragma unroll
      for(int j=0;j<TN;j++) o[(rbase+i)*ldo + cbase+j] = acc[i][j];
  } else if constexpr(EPI==3){
    const float* Dv = (const float*)aux + (long)bz*auxBatch;
    unsigned short* o = (unsigned short*)out + (long)bz*outBatch;
    #pragma unroll
    for(int i=0;i<TM;i++){ const float inv = 1.f/(Dv[rbase+i]+1e-8f);
      #pragma unroll
      for(int j=0;j<TN;j++) o[(rbase+i)*ldo + cbase+j] = f2b(acc[i][j]*inv);
    }
  } else { // EPI==4: +bias, output dtype per flag
    const float* bias = (const float*)aux;
    const int f = *flagp;
    if (f){
      float* o = (float*)out;
      #pragma unroll
      for(int i=0;i<TM;i++)
        #pragma unroll
        for(int j=0;j<TN;j++)
          o[(rbase+i)*ldo + cbase+j] = acc[i][j] + bias[cbase+j];
    } else {
      unsigned short* o = (unsigned short*)out;
      #pragma unroll
      for(int i=0;i<TM;i++)
        #pragma unroll
        for(int j=0;j<TN;j++)
          o[(rbase+i)*ldo + cbase+j] = f2b(acc[i][j] + bias[cbase+j]);
    }
  }
}

// ---------------- small kernels ----------------
__global__ void xd_kernel(const float* __restrict__ KQ, float* __restrict__ xd){
  const int t = blockIdx.x*4 + (threadIdx.x>>6);
  const int lane = threadIdx.x & 63;
  const float* row = KQ + (long)t*1536;
  float sk=0.f, sq=0.f;
  #pragma unroll
  for(int j=0;j<12;j++){
    const float a = row[lane + 64*j];       sk += a*a;
    const float b = row[768 + lane + 64*j]; sq += b*b;
  }
  for(int off=32; off; off>>=1){ sk += __shfl_down(sk,off); sq += __shfl_down(sq,off); }
  if(lane==0){ xd[t] = 0.5f*sk; xd[NTOK + t] = 0.5f*sq; }
}
__global__ void ksum_kernel(const unsigned short* __restrict__ kp, float* __restrict__ ksum){
  const int b = blockIdx.y;
  const int c = blockIdx.x*64 + (threadIdx.x & 63);
  const int r = threadIdx.x >> 6;
  const unsigned short* base = kp + (long)b*4096*384;
  float acc = 0.f;
  for(int t=r; t<4096; t+=4) acc += b2f(base[(long)t*384 + c]);
  __shared__ float red[4][64];
  red[r][threadIdx.x & 63] = acc;
  __syncthreads();
  if(r==0) ksum[b*384 + c] = red[0][threadIdx.x&63]+red[1][threadIdx.x&63]
                            +red[2][threadIdx.x&63]+red[3][threadIdx.x&63];
}
__global__ void d_kernel(const unsigned short* __restrict__ qp,
                         const float* __restrict__ ksum, float* __restrict__ Dv){
  const int t = blockIdx.x*4 + (threadIdx.x>>6);
  const int lane = threadIdx.x & 63;
  const int b = t >> 12;
  const unsigned short* row = qp + (long)t*384;
  const float* ks = ksum + b*384;
  float acc = 0.f;
  #pragma unroll
  for(int j=0;j<6;j++){ const int m = lane + 64*j; acc += b2f(row[m])*ks[m]; }
  for(int off=32; off; off>>=1) acc += __shfl_down(acc,off);
  if(lane==0) Dv[t] = acc;
}

// ---------------- launcher ----------------
extern "C" void kernel_launch(void* const* d_in, const int* in_sizes, int n_in,
                              void* d_out, int out_size, void* d_ws, size_t ws_size,
                              hipStream_t stream){
  const void* x       = d_in[0];
  const void* kqv_w1  = d_in[1];
  const void* kqv_w2  = d_in[2];
  const void* kqv_b   = d_in[3];
  const void* proj_w1 = d_in[4];
  const void* proj_w2 = d_in[5];
  const void* proj_b  = d_in[6];
  const void* w       = d_in[7];
  char* ws = (char*)d_ws;

  // workspace layout (bytes, 256-aligned). x32 aliases kp/qp/Y (disjoint lifetimes).
  const size_t o_Wkqv  = 0;            // 768*2304 f32   =   7,077,888
  const size_t o_Wproj = 7077888;      // 768*768  f32   =   2,359,296
  const size_t o_wT    = 9437184;      // 768*384  f32   =   1,179,648
  const size_t o_b32   = 10616832;     // 3072 f32       =      12,288 (kqv_b @0, proj_b @2304)
  const size_t o_flag  = 10629120;     //                =         256
  const size_t o_KQ    = 10629376;     // 32768*1536 f32 = 201,326,592
  const size_t o_V     = 211955968;    // 32768*768 bf16 =  50,331,648
  const size_t o_xd    = 262287616;    // 2*32768 f32    =     262,144
  const size_t o_ksum  = 262549760;    // 8*384 f32      =      12,288
  const size_t o_kptvT = 262562048;    // 8*384*768 f32  =   9,437,184
  const size_t o_D     = 271999232;    // 32768 f32      =     131,072
  const size_t o_kp    = 272130304;    // 32768*384 bf16 =  25,165,824
  const size_t o_qp    = 297296128;    // 32768*384 bf16 =  25,165,824
  const size_t o_Y     = 322461952;    // 32768*768 bf16 =  50,331,648
  const size_t TOTAL   = 372793600;    // x32 (32768*768 f32 = 100,663,296) @ o_kp
  if (ws_size < TOTAL) return;   // visible failure signal: output stays zero

  float*          Wkqv  = (float*)(ws + o_Wkqv);
  float*          Wproj = (float*)(ws + o_Wproj);
  float*          wT    = (float*)(ws + o_wT);
  float*          b32   = (float*)(ws + o_b32);
  int*            flagp = (int*)(ws + o_flag);
  float*          KQ    = (float*)(ws + o_KQ);
  unsigned short* V     = (unsigned short*)(ws + o_V);
  float*          xd    = (float*)(ws + o_xd);
  float*          ksum  = (float*)(ws + o_ksum);
  float*          kptvT = (float*)(ws + o_kptvT);
  float*          Dv    = (float*)(ws + o_D);
  float*          x32   = (float*)(ws + o_kp);      // alias, dies after G1
  unsigned short* kp    = (unsigned short*)(ws + o_kp);
  unsigned short* qp    = (unsigned short*)(ws + o_qp);
  unsigned short* Y     = (unsigned short*)(ws + o_Y);
  unsigned short* outp  = (unsigned short*)d_out;

  detect_dtype<<<1, 256, 0, stream>>>((const unsigned int*)x, flagp);

  cvt_kernel<<<98304, 256, 0, stream>>>(x, x32, 25165824, flagp);
  cvt_kernel<<<9, 256, 0, stream>>>(kqv_b,  b32,        2304, flagp);
  cvt_kernel<<<3, 256, 0, stream>>>(proj_b, b32 + 2304,  768, flagp);

  build_wkqv <<<6912, 256, 0, stream>>>(kqv_w1, kqv_w2, Wkqv, flagp);
  build_wproj<<<2304, 256, 0, stream>>>(proj_w1, proj_w2, Wproj, flagp);
  transpose_w<<<1152, 256, 0, stream>>>(w, wT, flagp);

  // G1: KQV = X @ Wkqv + b  (M=32768, N=2304, K=768)
  gemm_k<128,128,8,8, float, float, false, 0>
    <<<dim3(18,256,1), 256, 0, stream>>>(x32, 768, 0L, Wkqv, 2304, 0L,
                                         768, 0, 0L, KQ, V, b32, 0L, flagp);
  xd_kernel<<<8192, 256, 0, stream>>>(KQ, xd);

  // G2: kp / qp = exp(KQ_part @ wT - xd)/sqrt(M)  (M=32768, N=384, K=768)
  gemm_k<128,128,8,8, float, float, false, 1>
    <<<dim3(3,256,1), 256, 0, stream>>>(KQ,       1536, 0L, wT, 384, 0L,
                                        768, 384, 0L, kp, nullptr, xd, 0L, flagp);
  gemm_k<128,128,8,8, float, float, false, 1>
    <<<dim3(3,256,1), 256, 0, stream>>>(KQ + 768, 1536, 0L, wT, 384, 0L,
                                        768, 384, 0L, qp, nullptr, xd + NTOK, 0L, flagp);

  ksum_kernel<<<dim3(6,8,1), 256, 0, stream>>>(kp, ksum);

  // G3: kptvT[b][m][n] = sum_t kp[t][m]*V[t][n]  (M=384, N=768, K=4096, batched)
  gemm_k<64,64,4,4, unsigned short, unsigned short, true, 2>
    <<<dim3(12,6,8), 256, 0, stream>>>(kp, 384, 1572864L, V, 768, 3145728L,
                                       4096, 768, 294912L, kptvT, nullptr, nullptr, 0L, flagp);

  d_kernel<<<8192, 256, 0, stream>>>(qp, ksum, Dv);

  // G4: Y = (qp @ kptvT)/(D+eps)  (M=4096, N=768, K=384, batched)
  gemm_k<128,128,8,8, unsigned short, float, false, 3>
    <<<dim3(6,32,8), 256, 0, stream>>>(qp, 384, 1572864L, kptvT, 768, 294912L,
                                       384, 768, 3145728L, Y, nullptr, Dv, 4096L, flagp);

  // G5: OUT = Y @ Wproj + bp  (M=32768, N=768, K=768), output dtype per flag
  gemm_k<128,128,8,8, unsigned short, float, false, 4>
    <<<dim3(6,256,1), 256, 0, stream>>>(Y, 768, 0L, Wproj, 768, 0L,
                                        768, 768, 0L, outp, nullptr, b32 + 2304, 0L, flagp);
}

// Round 3
// 678.814 us; speedup vs baseline: 5.4409x; 5.4409x over previous
//
#include <hip/hip_runtime.h>

// MonarchAttentionPerformer MI355X — round 3: MFMA everywhere.
// I/O confirmed fp32 (round 2 flag=1 path passed). Exp-sensitive GEMMs (G1,G2)
// in fp16 MFMA w/ fp32 accumulate; G3/G4/G5 in bf16 MFMA.
// All MFMA operands K-contiguous:
//   G1: x16[t][d] @ WkqvT[c][d]   -> KQ f16 [t][1536], V^T bf16 [n][t]
//   G2: KQ       @ w16[m][d]      -> kpT bf16 [m][t] (transposed), qp bf16 [t][m]
//   G3: V^T[n][t] @ kpT[m][t]     -> kptv bf16 [b][n][m]
//   G4: qp[t][m] @ kptv[n][m]     -> Y bf16 [t][n]  (/ (D+eps))
//   G5: Y[t][n]  @ WprojT[o][n]   -> out fp32 [t][o] (+bias)

#define NTOK   32768
#define RSQRTM 0.05103103630798288f   // 1/sqrt(384)

typedef _Float16 f16;
typedef f16   f16x8 __attribute__((ext_vector_type(8)));
typedef f16   f16x4 __attribute__((ext_vector_type(4)));
typedef f16   f16x2 __attribute__((ext_vector_type(2)));
typedef short s16x8 __attribute__((ext_vector_type(8)));
typedef float f32x4 __attribute__((ext_vector_type(4)));

typedef const void __attribute__((address_space(1))) gv_t;
typedef void       __attribute__((address_space(3))) lv_t;
#define GLL16(g, l) __builtin_amdgcn_global_load_lds((gv_t*)(g), (lv_t*)(l), 16, 0, 0)

__device__ __forceinline__ float b2f(unsigned short u){
  union{unsigned int i; float f;} v; v.i = ((unsigned int)u)<<16; return v.f;
}
__device__ __forceinline__ unsigned short f2b(float f){
  union{float f; unsigned int i;} v; v.f = f;
  unsigned int x = v.i;
  x += 0x7fffu + ((x>>16)&1u);
  return (unsigned short)(x>>16);
}

template<typename T> struct MfmaOp;
template<> struct MfmaOp<f16> {
  typedef f16x8 frag;
  static __device__ __forceinline__ f32x4 run(frag a, frag b, f32x4 c){
    return __builtin_amdgcn_mfma_f32_16x16x32_f16(a, b, c, 0, 0, 0);
  }
};
template<> struct MfmaOp<short> {   // bf16 payload in shorts
  typedef s16x8 frag;
  static __device__ __forceinline__ f32x4 run(frag a, frag b, f32x4 c){
    return __builtin_amdgcn_mfma_f32_16x16x32_bf16(a, b, c, 0, 0, 0);
  }
};

// ---------------- converters / builders ----------------
__global__ void cvt16(const float4* __restrict__ src, f16* __restrict__ dst, int n4){
  const int i = blockIdx.x*256 + threadIdx.x;
  if (i >= n4) return;
  const float4 v = src[i];
  f16x4 h; h[0]=(f16)v.x; h[1]=(f16)v.y; h[2]=(f16)v.z; h[3]=(f16)v.w;
  *reinterpret_cast<f16x4*>(dst + 4*(long)i) = h;
}
// WkqvT[j][i] = dense[i][j], i=k*192+p (in), j=s*4+l (out of 2304)
__global__ void build_wkqvT(const float* __restrict__ w1, const float* __restrict__ w2,
                            f16* __restrict__ Wt){
  const int idx = blockIdx.x*256 + threadIdx.x;   // 2304*768
  const int j = idx / 768, i = idx % 768;
  const int k = i / 192, p = i % 192;
  const int s = j >> 2,  l = j & 3;
  float acc = 0.f;
  #pragma unroll 4
  for(int u=0; u<48; ++u)
    acc += w1[(k*192 + l*48+u)*192 + p] * w2[(l*576+s)*192 + 4*u+k];
  Wt[idx] = (f16)acc;
}
__global__ void build_wprojT(const float* __restrict__ w1, const float* __restrict__ w2,
                             unsigned short* __restrict__ Wt){
  const int idx = blockIdx.x*256 + threadIdx.x;   // 768*768
  const int j = idx / 768, i = idx % 768;
  const int k = i / 192, p = i % 192;
  const int s = j >> 2,  l = j & 3;
  float acc = 0.f;
  #pragma unroll 4
  for(int u=0; u<48; ++u)
    acc += w1[(k*192 + l*48+u)*192 + p] * w2[(l*192+s)*192 + 4*u+k];
  Wt[idx] = f2b(acc);
}

// ---------------- MFMA GEMM ----------------
// C[M][N] = A[M][K] * Bt[N][K]^T, 256 thr = 4 waves (2x2), BK=32, 16x16x32 MFMA.
// A,Bt element type T (f16 or short=bf16), K-contiguous rows.
// EPI: 0 G1 (n0<1536: KQ f16 +bias ; else V^T bf16 +bias, ld 32768)
//      1 G2k: exp(acc-xd[t])*RSQRTM -> bf16 transposed (ldo)
//      2 G2q: exp(acc-xd[t])*RSQRTM -> bf16 normal (ldo)
//      3 G3 : bf16 normal (batched)
//      4 G4 : acc/(D[t]+1e-8) -> bf16 normal (batched)
//      5 G5 : acc+bias[n] -> fp32 normal
template<typename T, int BM, int BN, int EPI>
__global__ __launch_bounds__(256)
void mgemm(const T* __restrict__ A, int lda, long aB,
           const T* __restrict__ Bt, int ldb, long bB,
           int K, void* __restrict__ out, int ldo, long outB,
           void* __restrict__ out2,
           const float* __restrict__ aux, long auxB){
  constexpr int MT = BM/32, NT = BN/32;
  constexpr int IA = BM/64, IB = BN/64;   // global_load_lds insts per wave
  __shared__ T As[BM*32];
  __shared__ T Bs[BN*32];
  typedef typename MfmaOp<T>::frag frag_t;

  const int tid = threadIdx.x, lane = tid & 63, w = tid >> 6;
  const int wm = w >> 1, wn = w & 1;
  const int bz = blockIdx.z;
  const long m0 = (long)blockIdx.y * BM;
  const int  n0 = blockIdx.x * BN;
  const T* Ab = A  + (long)bz*aB;
  const T* Bb = Bt + (long)bz*bB;

  f32x4 acc[MT][NT];
  const f32x4 zero = {0.f, 0.f, 0.f, 0.f};
  #pragma unroll
  for(int i=0;i<MT;i++)
    #pragma unroll
    for(int j=0;j<NT;j++) acc[i][j] = zero;

  for (int k0 = 0; k0 < K; k0 += 32){
    __syncthreads();
    #pragma unroll
    for (int i = 0; i < IA; ++i){
      const int e = (w*IA + i)*64 + lane;
      const int m = e >> 2, j = e & 3;
      GLL16(Ab + (m0 + m)*lda + k0 + j*8, As + (size_t)(w*IA + i)*512);
    }
    #pragma unroll
    for (int i = 0; i < IB; ++i){
      const int e = (w*IB + i)*64 + lane;
      const int n = e >> 2, j = e & 3;
      GLL16(Bb + (long)(n0 + n)*ldb + k0 + j*8, Bs + (size_t)(w*IB + i)*512);
    }
    __syncthreads();

    frag_t a[MT], b[NT];
    #pragma unroll
    for (int mt=0; mt<MT; ++mt)
      a[mt] = *reinterpret_cast<const frag_t*>(
        &As[(wm*MT*16 + mt*16 + (lane&15))*32 + (lane>>4)*8]);
    #pragma unroll
    for (int nt=0; nt<NT; ++nt)
      b[nt] = *reinterpret_cast<const frag_t*>(
        &Bs[(wn*NT*16 + nt*16 + (lane&15))*32 + (lane>>4)*8]);
    #pragma unroll
    for (int mt=0; mt<MT; ++mt)
      #pragma unroll
      for (int nt=0; nt<NT; ++nt)
        acc[mt][nt] = MfmaOp<T>::run(a[mt], b[nt], acc[mt][nt]);
  }

  // ---- epilogue ----
  const int q = lane >> 4, ln = lane & 15;
  #pragma unroll
  for (int mt=0; mt<MT; ++mt){
    const long mbase = m0 + wm*MT*16 + mt*16 + q*4;
    float xv[4];
    if constexpr(EPI==1 || EPI==2){
      #pragma unroll
      for(int r=0;r<4;r++) xv[r] = aux[mbase + r];
    }
    if constexpr(EPI==4){
      #pragma unroll
      for(int r=0;r<4;r++) xv[r] = 1.f/(aux[bz*auxB + mbase + r] + 1e-8f);
    }
    #pragma unroll
    for (int nt=0; nt<NT; ++nt){
      const int n = n0 + wn*NT*16 + nt*16 + ln;
      const f32x4 c = acc[mt][nt];
      if constexpr(EPI==0){
        if (n0 < 1536){
          f16* KQ = (f16*)out;
          const float bv = aux[n];
          #pragma unroll
          for(int r=0;r<4;r++) KQ[(mbase+r)*1536 + n] = (f16)(c[r] + bv);
        } else {
          unsigned short* VT = (unsigned short*)out2;
          const float bv = aux[n];
          ushort4 v;
          v.x = f2b(c[0]+bv); v.y = f2b(c[1]+bv); v.z = f2b(c[2]+bv); v.w = f2b(c[3]+bv);
          *reinterpret_cast<ushort4*>(&VT[(long)(n-1536)*32768 + mbase]) = v;
        }
      } else if constexpr(EPI==1){
        unsigned short* o = (unsigned short*)out;
        ushort4 v;
        v.x = f2b(__expf(c[0]-xv[0])*RSQRTM);
        v.y = f2b(__expf(c[1]-xv[1])*RSQRTM);
        v.z = f2b(__expf(c[2]-xv[2])*RSQRTM);
        v.w = f2b(__expf(c[3]-xv[3])*RSQRTM);
        *reinterpret_cast<ushort4*>(&o[(long)n*ldo + mbase]) = v;
      } else if constexpr(EPI==2){
        unsigned short* o = (unsigned short*)out;
        #pragma unroll
        for(int r=0;r<4;r++)
          o[(mbase+r)*ldo + n] = f2b(__expf(c[r]-xv[r])*RSQRTM);
      } else if constexpr(EPI==3){
        unsigned short* o = (unsigned short*)out + (long)bz*outB;
        #pragma unroll
        for(int r=0;r<4;r++) o[(mbase+r)*ldo + n] = f2b(c[r]);
      } else if constexpr(EPI==4){
        unsigned short* o = (unsigned short*)out + (long)bz*outB;
        #pragma unroll
        for(int r=0;r<4;r++) o[(mbase+r)*ldo + n] = f2b(c[r]*xv[r]);
      } else {
        float* o = (float*)out;
        const float bv = aux[n];
        #pragma unroll
        for(int r=0;r<4;r++) o[(mbase+r)*ldo + n] = c[r] + bv;
      }
    }
  }
}

// ---------------- small kernels ----------------
__global__ void xd_kernel(const f16* __restrict__ KQ, float* __restrict__ xd){
  const int t = blockIdx.x*4 + (threadIdx.x>>6);
  const int lane = threadIdx.x & 63;
  const f16* row = KQ + (long)t*1536;
  float sk=0.f, sq=0.f;
  #pragma unroll
  for(int j=0;j<6;j++){
    const f16x2 a = *reinterpret_cast<const f16x2*>(&row[lane*2 + j*128]);
    const f16x2 b = *reinterpret_cast<const f16x2*>(&row[768 + lane*2 + j*128]);
    const float a0=(float)a[0], a1=(float)a[1], b0=(float)b[0], b1=(float)b[1];
    sk += a0*a0 + a1*a1;  sq += b0*b0 + b1*b1;
  }
  for(int off=32; off; off>>=1){ sk += __shfl_down(sk,off); sq += __shfl_down(sq,off); }
  if(lane==0){ xd[t] = 0.5f*sk; xd[NTOK + t] = 0.5f*sq; }
}
// ksum[b*384+m] = sum_t kpT[m][b*4096+t]
__global__ void ksum_kernel(const unsigned short* __restrict__ kpT, float* __restrict__ ksum){
  const int lane = threadIdx.x & 63, w = threadIdx.x >> 6;
  const int id = blockIdx.x*4 + w;            // 0..3071
  const int m = id % 384, b = id / 384;
  const unsigned short* base = kpT + (long)m*32768 + b*4096;
  float acc = 0.f;
  #pragma unroll
  for(int j=0;j<16;j++){
    const ushort4 v = *reinterpret_cast<const ushort4*>(&base[lane*4 + j*256]);
    acc += b2f(v.x)+b2f(v.y)+b2f(v.z)+b2f(v.w);
  }
  for(int off=32; off; off>>=1) acc += __shfl_down(acc,off);
  if(lane==0) ksum[id] = acc;
}
__global__ void d_kernel(const unsigned short* __restrict__ qp,
                         const float* __restrict__ ksum, float* __restrict__ Dv){
  const int t = blockIdx.x*4 + (threadIdx.x>>6);
  const int lane = threadIdx.x & 63;
  const int b = t >> 12;
  const unsigned short* row = qp + (long)t*384;
  const float* ks = ksum + b*384;
  float acc = 0.f;
  #pragma unroll
  for(int j=0;j<6;j++){ const int m = lane + 64*j; acc += b2f(row[m])*ks[m]; }
  for(int off=32; off; off>>=1) acc += __shfl_down(acc,off);
  if(lane==0) Dv[t] = acc;
}

// ---------------- launcher ----------------
extern "C" void kernel_launch(void* const* d_in, const int* in_sizes, int n_in,
                              void* d_out, int out_size, void* d_ws, size_t ws_size,
                              hipStream_t stream){
  const float* x       = (const float*)d_in[0];
  const float* kqv_w1  = (const float*)d_in[1];
  const float* kqv_w2  = (const float*)d_in[2];
  const float* kqv_b   = (const float*)d_in[3];
  const float* proj_w1 = (const float*)d_in[4];
  const float* proj_w2 = (const float*)d_in[5];
  const float* proj_b  = (const float*)d_in[6];
  const float* w       = (const float*)d_in[7];
  char* ws = (char*)d_ws;

  const size_t o_WkqvT  = 0;          // 2304*768 f16  =  3,538,944
  const size_t o_WprojT = 3538944;    // 768*768 bf16  =  1,179,648
  const size_t o_w16    = 4718592;    // 384*768 f16   =    589,824
  const size_t o_x16    = 5308416;    // 32768*768 f16 = 50,331,648
  const size_t o_KQ     = 55640064;   // 32768*1536 f16=100,663,296
  const size_t o_VT     = 156303360;  // 768*32768 bf16= 50,331,648
  const size_t o_xd     = 206635008;  // 2*32768 f32   =    262,144
  const size_t o_kpT    = 206897152;  // 384*32768 bf16= 25,165,824
  const size_t o_qp     = 232062976;  // 32768*384 bf16= 25,165,824
  const size_t o_ksum   = 257228800;  // 3072 f32      =     12,288
  const size_t o_kptv   = 257241088;  // 8*768*384 bf16=  4,718,592
  const size_t o_Dv     = 261959680;  // 32768 f32     =    131,072
  const size_t o_Y      = 262090752;  // 32768*768 bf16= 50,331,648
  const size_t TOTAL    = 312422400;
  if (ws_size < TOTAL) return;

  f16*            WkqvT  = (f16*)(ws + o_WkqvT);
  short*          WprojT = (short*)(ws + o_WprojT);
  f16*            w16    = (f16*)(ws + o_w16);
  f16*            x16    = (f16*)(ws + o_x16);
  f16*            KQ     = (f16*)(ws + o_KQ);
  short*          VT     = (short*)(ws + o_VT);
  float*          xd     = (float*)(ws + o_xd);
  short*          kpT    = (short*)(ws + o_kpT);
  short*          qp     = (short*)(ws + o_qp);
  float*          ksum   = (float*)(ws + o_ksum);
  short*          kptv   = (short*)(ws + o_kptv);
  float*          Dv     = (float*)(ws + o_Dv);
  short*          Y      = (short*)(ws + o_Y);

  cvt16<<<24576, 256, 0, stream>>>((const float4*)x, x16, 6291456);
  cvt16<<<288,   256, 0, stream>>>((const float4*)w, w16, 73728);
  build_wkqvT <<<6912, 256, 0, stream>>>(kqv_w1, kqv_w2, WkqvT);
  build_wprojT<<<2304, 256, 0, stream>>>(proj_w1, proj_w2, (unsigned short*)WprojT);

  // G1: [32768 x 2304 x 768] fp16
  mgemm<f16,128,128,0><<<dim3(18,256,1), 256, 0, stream>>>(
      x16, 768, 0L, WkqvT, 768, 0L, 768, KQ, 1536, 0L, VT, kqv_b, 0L);
  xd_kernel<<<8192, 256, 0, stream>>>(KQ, xd);

  // G2: [32768 x 384 x 768] fp16 — kp (transposed out) and qp (normal out)
  mgemm<f16,128,128,1><<<dim3(3,256,1), 256, 0, stream>>>(
      KQ, 1536, 0L, w16, 768, 0L, 768, kpT, 32768, 0L, nullptr, xd, 0L);
  mgemm<f16,128,128,2><<<dim3(3,256,1), 256, 0, stream>>>(
      KQ + 768, 1536, 0L, w16, 768, 0L, 768, qp, 384, 0L, nullptr, xd + NTOK, 0L);

  ksum_kernel<<<768, 256, 0, stream>>>((const unsigned short*)kpT, ksum);

  // G3: kptv[b][n][m] = sum_t V^T[n][t]*kp[t][m]  [768 x 384 x 4096] x8, bf16
  mgemm<short,64,64,3><<<dim3(6,12,8), 256, 0, stream>>>(
      VT, 32768, 4096L, kpT, 32768, 4096L, 4096, kptv, 384, 294912L, nullptr, nullptr, 0L);

  d_kernel<<<8192, 256, 0, stream>>>((const unsigned short*)qp, ksum, Dv);

  // G4: Y[t][n] = (qp @ kptv^T)/(D+eps)  [4096 x 768 x 384] x8, bf16
  mgemm<short,128,128,4><<<dim3(6,32,8), 256, 0, stream>>>(
      qp, 384, 1572864L, kptv, 384, 294912L, 384, Y, 768, 3145728L, nullptr, Dv, 4096L);

  // G5: out = Y @ WprojT^T + bias  [32768 x 768 x 768] bf16 -> fp32
  mgemm<short,128,128,5><<<dim3(6,256,1), 256, 0, stream>>>(
      Y, 768, 0L, WprojT, 768, 0L, 768, d_out, 768, 0L, nullptr, proj_b, 0L);
}

// Round 4
// 651.537 us; speedup vs baseline: 5.6687x; 1.0419x over previous
//
#include <hip/hip_runtime.h>

// MonarchAttentionPerformer MI355X — round 4: BK=64 K-loop (32 MFMA/barrier),
// XOR-swizzled LDS (conflict-free ds_read_b128), split-K G3, epilogue-fused
// xd/ksum/D reductions (3 small kernels removed).
//
//   G1: x16[t][d] @ WkqvT[c][d]  -> KQ f16 [t][1536], V^T bf16 [n][t], xd atomics
//   G2k: KQ @ w16 -> kpT bf16 [m][t] + ksum atomics
//   G2q: KQ+768 @ w16 -> qp bf16 [t][m] + D atomics
//   G3: V^T @ kpT^T (split-K=4) -> kptv32 partials f32 -> reduce -> kptv bf16
//   G4: qp @ kptv^T / (D+eps) -> Y bf16
//   G5: Y @ WprojT^T + bias -> out fp32

#define NTOK   32768
#define RSQRTM 0.05103103630798288f   // 1/sqrt(384)

typedef _Float16 f16;
typedef f16   f16x8 __attribute__((ext_vector_type(8)));
typedef f16   f16x4 __attribute__((ext_vector_type(4)));
typedef short s16x8 __attribute__((ext_vector_type(8)));
typedef float f32x4 __attribute__((ext_vector_type(4)));

typedef const void __attribute__((address_space(1))) gv_t;
typedef void       __attribute__((address_space(3))) lv_t;
#define GLL16(g, l) __builtin_amdgcn_global_load_lds((gv_t*)(g), (lv_t*)(l), 16, 0, 0)

__device__ __forceinline__ float b2f(unsigned short u){
  union{unsigned int i; float f;} v; v.i = ((unsigned int)u)<<16; return v.f;
}
__device__ __forceinline__ unsigned short f2b(float f){
  union{float f; unsigned int i;} v; v.f = f;
  unsigned int x = v.i;
  x += 0x7fffu + ((x>>16)&1u);
  return (unsigned short)(x>>16);
}

template<typename T> struct MfmaOp;
template<> struct MfmaOp<f16> {
  typedef f16x8 frag;
  static __device__ __forceinline__ f32x4 run(frag a, frag b, f32x4 c){
    return __builtin_amdgcn_mfma_f32_16x16x32_f16(a, b, c, 0, 0, 0);
  }
};
template<> struct MfmaOp<short> {   // bf16 payload
  typedef s16x8 frag;
  static __device__ __forceinline__ f32x4 run(frag a, frag b, f32x4 c){
    return __builtin_amdgcn_mfma_f32_16x16x32_bf16(a, b, c, 0, 0, 0);
  }
};

// ---------------- converters / builders ----------------
__global__ void cvt16(const float4* __restrict__ src, f16* __restrict__ dst, int n4){
  const int i = blockIdx.x*256 + threadIdx.x;
  if (i >= n4) return;
  const float4 v = src[i];
  f16x4 h; h[0]=(f16)v.x; h[1]=(f16)v.y; h[2]=(f16)v.z; h[3]=(f16)v.w;
  *reinterpret_cast<f16x4*>(dst + 4*(long)i) = h;
}
__global__ void build_wkqvT(const float* __restrict__ w1, const float* __restrict__ w2,
                            f16* __restrict__ Wt){
  const int idx = blockIdx.x*256 + threadIdx.x;   // 2304*768
  const int j = idx / 768, i = idx % 768;
  const int k = i / 192, p = i % 192;
  const int s = j >> 2,  l = j & 3;
  float acc = 0.f;
  #pragma unroll 4
  for(int u=0; u<48; ++u)
    acc += w1[(k*192 + l*48+u)*192 + p] * w2[(l*576+s)*192 + 4*u+k];
  Wt[idx] = (f16)acc;
}
__global__ void build_wprojT(const float* __restrict__ w1, const float* __restrict__ w2,
                             unsigned short* __restrict__ Wt){
  const int idx = blockIdx.x*256 + threadIdx.x;   // 768*768
  const int j = idx / 768, i = idx % 768;
  const int k = i / 192, p = i % 192;
  const int s = j >> 2,  l = j & 3;
  float acc = 0.f;
  #pragma unroll 4
  for(int u=0; u<48; ++u)
    acc += w1[(k*192 + l*48+u)*192 + p] * w2[(l*192+s)*192 + 4*u+k];
  Wt[idx] = f2b(acc);
}
// kptv[b][i] = bf16( sum_s kptv32[(b*4+s)][i] )
__global__ void reduce_kptv(const float* __restrict__ p32, unsigned short* __restrict__ o){
  const int idx = blockIdx.x*256 + threadIdx.x;   // 8*294912
  const int b = idx / 294912, i = idx % 294912;
  const float* base = p32 + (long)b*4*294912 + i;
  o[idx] = f2b(base[0] + base[294912] + base[2*294912] + base[3*294912]);
}

// ---------------- MFMA GEMM, BK=64, XOR-swizzled LDS ----------------
// C[M][N] = A[M][K] * Bt[N][K]^T. 256 thr = 4 waves (2x2), 16x16x32 MFMA.
// LDS: row-major chunks of 8 elems; chunk j of row m stored at slot j^(m&7).
// EPI: 0 G1  (KQ f16 + V^T bf16 + bias; xd partials -> aux2 atomics)
//      1 G2k (exp -> kpT transposed; ksum partials -> aux2 atomics)
//      2 G2q (exp -> qp; D partials -> out2 atomics, ksum read from aux2)
//      3 G3  (fp32 partial store, split-K)
//      4 G4  (acc/(D[t]+1e-8) -> bf16, batched)
//      5 G5  (acc+bias -> fp32)
template<typename T, int BM, int BN, int EPI, int SPLIT>
__global__ __launch_bounds__(256)
void mgemm(const T* __restrict__ A, int lda, long aB,
           const T* __restrict__ Bt, int ldb, long bB,
           int K, void* __restrict__ out, int ldo, long outB,
           void* __restrict__ out2,
           const float* __restrict__ aux, long auxB,
           float* __restrict__ aux2){
  constexpr int MT = BM/32, NT = BN/32;
  constexpr int IA = BM/32, IB = BN/32;   // GLL16 insts per wave per iter
  __shared__ T As[BM*64];
  __shared__ T Bs[BN*64];
  typedef typename MfmaOp<T>::frag frag_t;

  const int tid = threadIdx.x, lane = tid & 63, w = tid >> 6;
  const int wm = w >> 1, wn = w & 1;
  const int ln = lane & 15, q = lane >> 4;
  const int bz = blockIdx.z;
  const int batch = bz / SPLIT;
  const int kstart = (bz % SPLIT) * K;
  const long m0 = (long)blockIdx.y * BM;
  const int  n0 = blockIdx.x * BN;
  const T* Ab = A  + (long)batch*aB;
  const T* Bb = Bt + (long)batch*bB;

  f32x4 acc[MT][NT];
  const f32x4 zero = {0.f, 0.f, 0.f, 0.f};
  #pragma unroll
  for(int i=0;i<MT;i++)
    #pragma unroll
    for(int j=0;j<NT;j++) acc[i][j] = zero;

  for (int k0 = kstart; k0 < kstart + K; k0 += 64){
    __syncthreads();
    #pragma unroll
    for (int i = 0; i < IA; ++i){
      const int e = (w*IA + i)*64 + lane;
      const int m = e >> 3, j = (e & 7) ^ (m & 7);
      GLL16(Ab + (m0 + m)*lda + k0 + j*8, As + (size_t)(w*IA + i)*512);
    }
    #pragma unroll
    for (int i = 0; i < IB; ++i){
      const int e = (w*IB + i)*64 + lane;
      const int n = e >> 3, j = (e & 7) ^ (n & 7);
      GLL16(Bb + (long)(n0 + n)*ldb + k0 + j*8, Bs + (size_t)(w*IB + i)*512);
    }
    __syncthreads();

    #pragma unroll
    for (int kk = 0; kk < 2; ++kk){
      frag_t a[MT], b[NT];
      #pragma unroll
      for (int mt=0; mt<MT; ++mt){
        const int r = wm*MT*16 + mt*16 + ln;
        a[mt] = *reinterpret_cast<const frag_t*>(&As[(r*8 + ((kk*4+q) ^ (r&7)))*8]);
      }
      #pragma unroll
      for (int nt=0; nt<NT; ++nt){
        const int r = wn*NT*16 + nt*16 + ln;
        b[nt] = *reinterpret_cast<const frag_t*>(&Bs[(r*8 + ((kk*4+q) ^ (r&7)))*8]);
      }
      #pragma unroll
      for (int mt=0; mt<MT; ++mt)
        #pragma unroll
        for (int nt=0; nt<NT; ++nt)
          acc[mt][nt] = MfmaOp<T>::run(a[mt], b[nt], acc[mt][nt]);
    }
  }

  // ---- epilogues ----
  if constexpr(EPI==1){               // G2k: kpT + ksum fusion
    const int b = (int)(m0 >> 12);
    float cs[NT];
    #pragma unroll
    for(int nt=0;nt<NT;nt++) cs[nt]=0.f;
    #pragma unroll
    for (int mt=0; mt<MT; ++mt){
      const long mbase = m0 + wm*MT*16 + mt*16 + q*4;
      float xv[4];
      #pragma unroll
      for(int r=0;r<4;r++) xv[r] = aux[mbase + r];
      #pragma unroll
      for (int nt=0; nt<NT; ++nt){
        const int n = n0 + wn*NT*16 + nt*16 + ln;
        const f32x4 c = acc[mt][nt];
        ushort4 v;
        v.x = f2b(__expf(c[0]-xv[0])*RSQRTM);
        v.y = f2b(__expf(c[1]-xv[1])*RSQRTM);
        v.z = f2b(__expf(c[2]-xv[2])*RSQRTM);
        v.w = f2b(__expf(c[3]-xv[3])*RSQRTM);
        *reinterpret_cast<ushort4*>(&((unsigned short*)out)[(long)n*ldo + mbase]) = v;
        cs[nt] += b2f(v.x)+b2f(v.y)+b2f(v.z)+b2f(v.w);
      }
    }
    #pragma unroll
    for (int nt=0; nt<NT; ++nt){
      cs[nt] += __shfl_xor(cs[nt], 16);
      cs[nt] += __shfl_xor(cs[nt], 32);
      if (lane < 16)
        atomicAdd(&aux2[b*384 + n0 + wn*NT*16 + nt*16 + lane], cs[nt]);
    }
    return;
  }

  #pragma unroll
  for (int mt=0; mt<MT; ++mt){
    const long mbase = m0 + wm*MT*16 + mt*16 + q*4;
    if constexpr(EPI==0){             // G1: KQ/V + bias + xd fusion
      const int nw = n0 + wn*NT*16;
      const int part = nw / 768;      // 0=K, 1=Q, 2=V (wave-uniform)
      float p[4] = {0.f,0.f,0.f,0.f};
      #pragma unroll
      for (int nt=0; nt<NT; ++nt){
        const int n = nw + nt*16 + ln;
        const f32x4 c = acc[mt][nt];
        const float bv = aux[n];
        if (part < 2){
          f16* KQ = (f16*)out;
          #pragma unroll
          for(int r=0;r<4;r++){
            const f16 h = (f16)(c[r] + bv);
            KQ[(mbase+r)*1536 + n] = h;
            const float hf = (float)h;
            p[r] += hf*hf;
          }
        } else {
          unsigned short* VT = (unsigned short*)out2;
          ushort4 v;
          v.x = f2b(c[0]+bv); v.y = f2b(c[1]+bv); v.z = f2b(c[2]+bv); v.w = f2b(c[3]+bv);
          *reinterpret_cast<ushort4*>(&VT[(long)(n-1536)*32768 + mbase]) = v;
        }
      }
      if (part < 2){
        #pragma unroll
        for(int r=0;r<4;r++){
          #pragma unroll
          for(int mask=1; mask<16; mask<<=1) p[r] += __shfl_xor(p[r], mask);
        }
        if (ln == 0){
          #pragma unroll
          for(int r=0;r<4;r++)
            atomicAdd(&aux2[part*NTOK + mbase + r], 0.5f*p[r]);
        }
      }
    } else if constexpr(EPI==2){      // G2q: qp + D fusion
      const int b = (int)(m0 >> 12);
      float xv[4], dp[4] = {0.f,0.f,0.f,0.f};
      #pragma unroll
      for(int r=0;r<4;r++) xv[r] = aux[mbase + r];
      #pragma unroll
      for (int nt=0; nt<NT; ++nt){
        const int n = n0 + wn*NT*16 + nt*16 + ln;
        const f32x4 c = acc[mt][nt];
        const float ksn = aux2[b*384 + n];
        #pragma unroll
        for(int r=0;r<4;r++){
          const unsigned short h = f2b(__expf(c[r]-xv[r])*RSQRTM);
          ((unsigned short*)out)[(mbase+r)*ldo + n] = h;
          dp[r] += b2f(h)*ksn;
        }
      }
      #pragma unroll
      for(int r=0;r<4;r++){
        #pragma unroll
        for(int mask=1; mask<16; mask<<=1) dp[r] += __shfl_xor(dp[r], mask);
      }
      if (ln == 0){
        #pragma unroll
        for(int r=0;r<4;r++)
          atomicAdd(&((float*)out2)[mbase + r], dp[r]);
      }
    } else if constexpr(EPI==3){      // G3: fp32 partial
      float* o = (float*)out + (long)bz*outB;
      #pragma unroll
      for (int nt=0; nt<NT; ++nt){
        const int n = n0 + wn*NT*16 + nt*16 + ln;
        const f32x4 c = acc[mt][nt];
        #pragma unroll
        for(int r=0;r<4;r++) o[(mbase+r)*ldo + n] = c[r];
      }
    } else if constexpr(EPI==4){      // G4: /(D+eps) -> bf16
      unsigned short* o = (unsigned short*)out + (long)bz*outB;
      float xv[4];
      #pragma unroll
      for(int r=0;r<4;r++) xv[r] = 1.f/(aux[bz*auxB + mbase + r] + 1e-8f);
      #pragma unroll
      for (int nt=0; nt<NT; ++nt){
        const int n = n0 + wn*NT*16 + nt*16 + ln;
        const f32x4 c = acc[mt][nt];
        #pragma unroll
        for(int r=0;r<4;r++) o[(mbase+r)*ldo + n] = f2b(c[r]*xv[r]);
      }
    } else if constexpr(EPI==5){      // G5: +bias -> fp32
      float* o = (float*)out;
      #pragma unroll
      for (int nt=0; nt<NT; ++nt){
        const int n = n0 + wn*NT*16 + nt*16 + ln;
        const f32x4 c = acc[mt][nt];
        const float bv = aux[n];
        #pragma unroll
        for(int r=0;r<4;r++) o[(mbase+r)*ldo + n] = c[r] + bv;
      }
    }
  }
}

// ---------------- launcher ----------------
extern "C" void kernel_launch(void* const* d_in, const int* in_sizes, int n_in,
                              void* d_out, int out_size, void* d_ws, size_t ws_size,
                              hipStream_t stream){
  (void)in_sizes; (void)n_in; (void)out_size;
  const float* x       = (const float*)d_in[0];
  const float* kqv_w1  = (const float*)d_in[1];
  const float* kqv_w2  = (const float*)d_in[2];
  const float* kqv_b   = (const float*)d_in[3];
  const float* proj_w1 = (const float*)d_in[4];
  const float* proj_w2 = (const float*)d_in[5];
  const float* proj_b  = (const float*)d_in[6];
  const float* w       = (const float*)d_in[7];
  char* ws = (char*)d_ws;

  const size_t o_WkqvT  = 0;          // 2304*768 f16   =   3,538,944
  const size_t o_WprojT = 3538944;    // 768*768 bf16   =   1,179,648
  const size_t o_w16    = 4718592;    // 384*768 f16    =     589,824
  const size_t o_x16    = 5308416;    // 32768*768 f16  =  50,331,648
  const size_t o_KQ     = 55640064;   // 32768*1536 f16 = 100,663,296
  const size_t o_VT     = 156303360;  // 768*32768 bf16 =  50,331,648
  const size_t o_xd     = 206635008;  // 2*32768 f32    =     262,144 ┐
  const size_t o_ksum   = 206897152;  // 3072 f32       =      12,288 │ zero block
  const size_t o_Dv     = 206909440;  // 32768 f32      =     131,072 ┘
  const size_t o_kpT    = 207040512;  // 384*32768 bf16 =  25,165,824
  const size_t o_qp     = 232206336;  // 32768*384 bf16 =  25,165,824
  const size_t o_kptv32 = 257372160;  // 32*294912 f32  =  37,748,736
  const size_t o_kptv   = 295120896;  // 8*294912 bf16  =   4,718,592
  const size_t o_Y      = 299839488;  // 32768*768 bf16 =  50,331,648
  const size_t TOTAL    = 350171136;
  if (ws_size < TOTAL) return;

  f16*            WkqvT  = (f16*)(ws + o_WkqvT);
  short*          WprojT = (short*)(ws + o_WprojT);
  f16*            w16    = (f16*)(ws + o_w16);
  f16*            x16    = (f16*)(ws + o_x16);
  f16*            KQ     = (f16*)(ws + o_KQ);
  short*          VT     = (short*)(ws + o_VT);
  float*          xd     = (float*)(ws + o_xd);
  float*          ksum   = (float*)(ws + o_ksum);
  float*          Dv     = (float*)(ws + o_Dv);
  short*          kpT    = (short*)(ws + o_kpT);
  short*          qp     = (short*)(ws + o_qp);
  float*          kptv32 = (float*)(ws + o_kptv32);
  unsigned short* kptv   = (unsigned short*)(ws + o_kptv);
  short*          Y      = (short*)(ws + o_Y);

  hipMemsetAsync(ws + o_xd, 0, 405504, stream);   // xd + ksum + Dv

  cvt16<<<24576, 256, 0, stream>>>((const float4*)x, x16, 6291456);
  cvt16<<<288,   256, 0, stream>>>((const float4*)w, w16, 73728);
  build_wkqvT <<<6912, 256, 0, stream>>>(kqv_w1, kqv_w2, WkqvT);
  build_wprojT<<<2304, 256, 0, stream>>>(proj_w1, proj_w2, (unsigned short*)WprojT);

  // G1: [32768 x 2304 x 768] f16 (+ xd fusion)
  mgemm<f16,128,128,0,1><<<dim3(18,256,1), 256, 0, stream>>>(
      x16, 768, 0L, WkqvT, 768, 0L, 768, KQ, 1536, 0L, VT, kqv_b, 0L, xd);

  // G2k: [32768 x 384 x 768] -> kpT (+ ksum fusion)
  mgemm<f16,128,128,1,1><<<dim3(3,256,1), 256, 0, stream>>>(
      KQ, 1536, 0L, w16, 768, 0L, 768, kpT, 32768, 0L, nullptr, xd, 0L, ksum);

  // G2q: [32768 x 384 x 768] -> qp (+ D fusion; reads ksum)
  mgemm<f16,128,128,2,1><<<dim3(3,256,1), 256, 0, stream>>>(
      KQ + 768, 1536, 0L, w16, 768, 0L, 768, qp, 384, 0L, Dv, xd + NTOK, 0L, ksum);

  // G3: kptv32[b*4+s] partial = V^T[b] @ kpT[b]^T over K-chunk s  (split-K=4)
  mgemm<short,128,128,3,4><<<dim3(3,6,32), 256, 0, stream>>>(
      VT, 32768, 4096L, kpT, 32768, 4096L, 1024, kptv32, 384, 294912L,
      nullptr, nullptr, 0L, nullptr);
  reduce_kptv<<<9216, 256, 0, stream>>>(kptv32, kptv);

  // G4: Y = (qp @ kptv^T)/(D+eps)  [4096 x 768 x 384] x8
  mgemm<short,128,128,4,1><<<dim3(6,32,8), 256, 0, stream>>>(
      qp, 384, 1572864L, (short*)kptv, 384, 294912L, 384, Y, 768, 3145728L,
      nullptr, Dv, 4096L, nullptr);

  // G5: out = Y @ WprojT^T + bias  [32768 x 768 x 768] -> fp32
  mgemm<short,128,128,5,1><<<dim3(6,256,1), 256, 0, stream>>>(
      Y, 768, 0L, WprojT, 768, 0L, 768, d_out, 768, 0L, nullptr, proj_b, 0L, nullptr);
}